// Round 1
// baseline (173.337 us; speedup 1.0000x reference)
//
#include <hip/hip_runtime.h>

#define BN_EPS 1e-5f

constexpr int Bb = 2;
constexpr int Cc = 64;
constexpr int Nn = 32768;
constexpr int Kk = 16;
constexpr int Oo = 64;

// Kernel 1: t[b][n][o] = relu(inv[o] * (W[o,:] . feature[b,:,n]) + bias[o])
// t laid out n-major, o-contiguous: one point = contiguous 256B line.
__global__ __launch_bounds__(256) void spe_gemm_bn_relu(
    const float* __restrict__ feature, const float* __restrict__ W,
    const float* __restrict__ gamma, const float* __restrict__ beta,
    const float* __restrict__ rmean, const float* __restrict__ rvar,
    float* __restrict__ t)
{
    __shared__ float Wst[64 * 68];    // Wst[c*68 + o] = W[o][c]  (stride 68: 16B-aligned float4 rows, no read conflicts)
    __shared__ float feats[64 * 64];  // feats[c*64 + nl]
    const int tid = threadIdx.x;
    const int blk = blockIdx.x;       // 1024 blocks: b * 512 + ntile
    const int b   = blk >> 9;
    const int n0  = (blk & 511) << 6;

    // Stage W transposed + feature tile (both coalesced 256B global reads)
    {
        const int lo = tid & 63;   // lane-contiguous dim
        const int hi = tid >> 6;   // 0..3
        #pragma unroll
        for (int i = 0; i < 16; ++i) {
            const int o = hi + i * 4;
            Wst[lo * 68 + o] = W[o * 64 + lo];      // read W[o][c=lo] coalesced
        }
        const float* fp = feature + (size_t)b * Cc * Nn + n0 + lo;
        #pragma unroll
        for (int i = 0; i < 16; ++i) {
            const int c = hi + i * 4;
            feats[c * 64 + lo] = fp[(size_t)c * Nn]; // coalesced per c-row
        }
    }
    __syncthreads();

    const int tx = tid & 15;   // o-group
    const int ty = tid >> 4;   // n-group 0..15
    const int o0  = tx * 4;
    const int nl0 = ty * 4;

    float acc[4][4];   // [jn][io]
    #pragma unroll
    for (int j = 0; j < 4; ++j)
        #pragma unroll
        for (int i = 0; i < 4; ++i) acc[j][i] = 0.0f;

    #pragma unroll
    for (int c = 0; c < 64; ++c) {
        const float4 a4 = *(const float4*)&Wst[c * 68 + o0];
        const float4 b4 = *(const float4*)&feats[c * 64 + nl0];
        const float av[4] = {a4.x, a4.y, a4.z, a4.w};
        const float bv[4] = {b4.x, b4.y, b4.z, b4.w};
        #pragma unroll
        for (int j = 0; j < 4; ++j)
            #pragma unroll
            for (int i = 0; i < 4; ++i)
                acc[j][i] = fmaf(av[i], bv[j], acc[j][i]);
    }

    // BN affine + ReLU epilogue
    const float4 g4 = *(const float4*)&gamma[o0];
    const float4 be4 = *(const float4*)&beta[o0];
    const float4 m4 = *(const float4*)&rmean[o0];
    const float4 v4 = *(const float4*)&rvar[o0];
    float inv[4], bias[4];
    inv[0] = g4.x / sqrtf(v4.x + BN_EPS);
    inv[1] = g4.y / sqrtf(v4.y + BN_EPS);
    inv[2] = g4.z / sqrtf(v4.z + BN_EPS);
    inv[3] = g4.w / sqrtf(v4.w + BN_EPS);
    bias[0] = be4.x - m4.x * inv[0];
    bias[1] = be4.y - m4.y * inv[1];
    bias[2] = be4.z - m4.z * inv[2];
    bias[3] = be4.w - m4.w * inv[3];

    float* tp = t + ((size_t)b * Nn + n0 + nl0) * 64 + o0;
    #pragma unroll
    for (int j = 0; j < 4; ++j) {
        float4 ov;
        ov.x = fmaxf(fmaf(inv[0], acc[j][0], bias[0]), 0.0f);
        ov.y = fmaxf(fmaf(inv[1], acc[j][1], bias[1]), 0.0f);
        ov.z = fmaxf(fmaf(inv[2], acc[j][2], bias[2]), 0.0f);
        ov.w = fmaxf(fmaf(inv[3], acc[j][3], bias[3]), 0.0f);
        *(float4*)&tp[j * 64] = ov;   // 16B/lane, wave covers 4x256B rows
    }
}

// Kernel 2: out[b][o][n] = t[b][n][o] + sum_j t[b][idx[b][n][j]][o]
// One wave per point (lane = o): each gather is one contiguous 256B line.
__global__ __launch_bounds__(256) void spe_gather_sum(
    const float* __restrict__ t, const int* __restrict__ idx,
    float* __restrict__ out)
{
    __shared__ float s[64 * 65];      // s[nl*65 + o], stride 65 kills transpose conflicts
    const int tid  = threadIdx.x;
    const int lane = tid & 63;        // = o in gather phase
    const int w    = tid >> 6;        // wave 0..3
    const int blk  = blockIdx.x;
    const int b    = blk >> 9;
    const int n0   = (blk & 511) << 6;

    const float* tb = t + (size_t)b * Nn * 64;
    #pragma unroll
    for (int it = 0; it < 16; ++it) {
        const int nl = w + it * 4;
        const int n  = n0 + nl;
        const int* ip = idx + ((size_t)b * Nn + n) * Kk;
        const int myidx = ip[lane & 15];            // one 64B transaction, 4-way dup
        float acc = tb[(size_t)n * 64 + lane];      // center tap
        #pragma unroll
        for (int j = 0; j < 16; ++j) {
            const int nj = __shfl(myidx, j);
            acc += tb[(size_t)nj * 64 + lane];      // 16 independent coalesced gathers
        }
        s[nl * 65 + lane] = acc;
    }
    __syncthreads();

    // transpose write-out: lanes over n => coalesced 256B stores
    const int nl = tid & 63;
    const int ob = tid >> 6;          // 0..3
    float* op = out + (size_t)b * Oo * Nn + n0 + nl;
    #pragma unroll
    for (int i = 0; i < 16; ++i) {
        const int o = ob + i * 4;
        op[(size_t)o * Nn] = s[nl * 65 + o];
    }
}

extern "C" void kernel_launch(void* const* d_in, const int* in_sizes, int n_in,
                              void* d_out, int out_size, void* d_ws, size_t ws_size,
                              hipStream_t stream) {
    const float* feature = (const float*)d_in[0];
    const int*   nidx    = (const int*)d_in[1];
    const float* W       = (const float*)d_in[2];
    const float* gamma   = (const float*)d_in[3];
    const float* beta    = (const float*)d_in[4];
    const float* rmean   = (const float*)d_in[5];
    const float* rvar    = (const float*)d_in[6];
    float* out = (float*)d_out;
    float* t   = (float*)d_ws;   // needs B*N*O*4 = 16 MiB

    const int nblocks = Bb * (Nn / 64);  // 1024
    spe_gemm_bn_relu<<<nblocks, 256, 0, stream>>>(feature, W, gamma, beta, rmean, rvar, t);
    spe_gather_sum<<<nblocks, 256, 0, stream>>>(t, nidx, out);
}

// Round 2
// 115.544 us; speedup vs baseline: 1.5002x; 1.5002x over previous
//
#include <hip/hip_runtime.h>

#define BN_EPS 1e-5f

constexpr int Bb = 2;
constexpr int Cc = 64;
constexpr int Nn = 32768;
constexpr int Kk = 16;
constexpr int Oo = 64;

// Kernel 1: t[b][n][o] = relu(inv[o] * (W[o,:] . feature[b,:,n]) + bias[o])
// t laid out n-major, o-contiguous: one point = contiguous 256B line.
__global__ __launch_bounds__(256) void spe_gemm_bn_relu(
    const float* __restrict__ feature, const float* __restrict__ W,
    const float* __restrict__ gamma, const float* __restrict__ beta,
    const float* __restrict__ rmean, const float* __restrict__ rvar,
    float* __restrict__ t)
{
    __shared__ float Wst[64 * 68];    // Wst[c*68 + o] = W[o][c]
    __shared__ float feats[64 * 64];  // feats[c*64 + nl]
    const int tid = threadIdx.x;
    const int blk = blockIdx.x;       // 1024 blocks: b * 512 + ntile
    const int b   = blk >> 9;
    const int n0  = (blk & 511) << 6;

    {
        const int lo = tid & 63;
        const int hi = tid >> 6;
        #pragma unroll
        for (int i = 0; i < 16; ++i) {
            const int o = hi + i * 4;
            Wst[lo * 68 + o] = W[o * 64 + lo];
        }
        const float* fp = feature + (size_t)b * Cc * Nn + n0 + lo;
        #pragma unroll
        for (int i = 0; i < 16; ++i) {
            const int c = hi + i * 4;
            feats[c * 64 + lo] = fp[(size_t)c * Nn];
        }
    }
    __syncthreads();

    const int tx = tid & 15;
    const int ty = tid >> 4;
    const int o0  = tx * 4;
    const int nl0 = ty * 4;

    float acc[4][4];
    #pragma unroll
    for (int j = 0; j < 4; ++j)
        #pragma unroll
        for (int i = 0; i < 4; ++i) acc[j][i] = 0.0f;

    #pragma unroll
    for (int c = 0; c < 64; ++c) {
        const float4 a4 = *(const float4*)&Wst[c * 68 + o0];
        const float4 b4 = *(const float4*)&feats[c * 64 + nl0];
        const float av[4] = {a4.x, a4.y, a4.z, a4.w};
        const float bv[4] = {b4.x, b4.y, b4.z, b4.w};
        #pragma unroll
        for (int j = 0; j < 4; ++j)
            #pragma unroll
            for (int i = 0; i < 4; ++i)
                acc[j][i] = fmaf(av[i], bv[j], acc[j][i]);
    }

    const float4 g4 = *(const float4*)&gamma[o0];
    const float4 be4 = *(const float4*)&beta[o0];
    const float4 m4 = *(const float4*)&rmean[o0];
    const float4 v4 = *(const float4*)&rvar[o0];
    float inv[4], bias[4];
    inv[0] = g4.x / sqrtf(v4.x + BN_EPS);
    inv[1] = g4.y / sqrtf(v4.y + BN_EPS);
    inv[2] = g4.z / sqrtf(v4.z + BN_EPS);
    inv[3] = g4.w / sqrtf(v4.w + BN_EPS);
    bias[0] = be4.x - m4.x * inv[0];
    bias[1] = be4.y - m4.y * inv[1];
    bias[2] = be4.z - m4.z * inv[2];
    bias[3] = be4.w - m4.w * inv[3];

    float* tp = t + ((size_t)b * Nn + n0 + nl0) * 64 + o0;
    #pragma unroll
    for (int j = 0; j < 4; ++j) {
        float4 ov;
        ov.x = fmaxf(fmaf(inv[0], acc[j][0], bias[0]), 0.0f);
        ov.y = fmaxf(fmaf(inv[1], acc[j][1], bias[1]), 0.0f);
        ov.z = fmaxf(fmaf(inv[2], acc[j][2], bias[2]), 0.0f);
        ov.w = fmaxf(fmaf(inv[3], acc[j][3], bias[3]), 0.0f);
        *(float4*)&tp[j * 64] = ov;
    }
}

// Kernel 2: out[b][o][n] = t[b][n][o] + sum_j t[b][idx[b][n][j]][o]
// 16 waves/block, each wave owns 4 points: lane = (p, q) with p=point-in-group,
// q=o-quad. 17 independent float4 gathers per wave => ~70 VGPRs of loads in
// flight (vs 4 with the old scalar version) -> latency fully hidden.
__global__ __launch_bounds__(1024) void spe_gather_sum(
    const float* __restrict__ t, const int* __restrict__ idx,
    float* __restrict__ out)
{
    __shared__ float s[64 * 65];      // s[nl*65 + o]; stride 65 -> conflict-free transpose
    const int tid  = threadIdx.x;
    const int wv   = tid >> 6;        // wave 0..15
    const int lane = tid & 63;
    const int p    = lane >> 4;       // 0..3 point within group
    const int q    = lane & 15;       // o-quad (o = q*4..q*4+3)
    const int blk  = blockIdx.x;
    const int b    = blk >> 9;
    const int n0   = (blk & 511) << 6;
    const int ng   = n0 + wv * 4;     // this wave's 4-point group base

    const float* tb = t + (size_t)b * Nn * 64;

    // 4 points x 16 neighbors = 64 ints, one fully-coalesced 256B load
    const int myidx = idx[((size_t)b * Nn + ng) * Kk + lane];

    const int n = ng + p;
    float4 acc = *(const float4*)&tb[(size_t)n * 64 + q * 4];   // center tap
    #pragma unroll
    for (int j = 0; j < 16; ++j) {
        const int nj = __shfl(myidx, p * 16 + j);
        const float4 v = *(const float4*)&tb[(size_t)nj * 64 + q * 4];
        acc.x += v.x; acc.y += v.y; acc.z += v.z; acc.w += v.w;
    }

    const int nl = wv * 4 + p;
    float* sp = &s[nl * 65 + q * 4];   // banks (nl + 4q + i) % 32: <=2-way, free
    sp[0] = acc.x; sp[1] = acc.y; sp[2] = acc.z; sp[3] = acc.w;
    __syncthreads();

    // transpose write-out: lanes over n => coalesced 256B stores
    const int nl2 = tid & 63;
    const int ob  = tid >> 6;          // 0..15
    float* op = out + (size_t)b * Oo * Nn + n0 + nl2;
    #pragma unroll
    for (int i = 0; i < 4; ++i) {
        const int o = ob * 4 + i;
        op[(size_t)o * Nn] = s[nl2 * 65 + o];
    }
}

extern "C" void kernel_launch(void* const* d_in, const int* in_sizes, int n_in,
                              void* d_out, int out_size, void* d_ws, size_t ws_size,
                              hipStream_t stream) {
    const float* feature = (const float*)d_in[0];
    const int*   nidx    = (const int*)d_in[1];
    const float* W       = (const float*)d_in[2];
    const float* gamma   = (const float*)d_in[3];
    const float* beta    = (const float*)d_in[4];
    const float* rmean   = (const float*)d_in[5];
    const float* rvar    = (const float*)d_in[6];
    float* out = (float*)d_out;
    float* t   = (float*)d_ws;   // B*N*O*4 = 16 MiB

    const int nblocks = Bb * (Nn / 64);  // 1024
    spe_gemm_bn_relu<<<nblocks, 256, 0, stream>>>(feature, W, gamma, beta, rmean, rvar, t);
    spe_gather_sum<<<nblocks, 1024, 0, stream>>>(t, nidx, out);
}

// Round 3
// 99.300 us; speedup vs baseline: 1.7456x; 1.1636x over previous
//
#include <hip/hip_runtime.h>

#define BN_EPS 1e-5f

constexpr int Bb = 2;
constexpr int Cc = 64;
constexpr int Nn = 32768;
constexpr int Kk = 16;
constexpr int Oo = 64;

__device__ __forceinline__ unsigned short f2bf(float f) {
    unsigned u = __float_as_uint(f);
    unsigned r = (u + 0x7FFFu + ((u >> 16) & 1u)) >> 16;   // round-to-nearest-even
    return (unsigned short)r;
}
__device__ __forceinline__ float bf2f(unsigned short h) {
    return __uint_as_float(((unsigned)h) << 16);
}

// Kernel 1: t[b][n][o] = bf16( relu(inv[o] * (W[o,:] . feature[b,:,n]) + bias[o]) )
// t laid out n-major, o-contiguous: one point = contiguous 128B bf16 line.
__global__ __launch_bounds__(256) void spe_gemm_bn_relu(
    const float* __restrict__ feature, const float* __restrict__ W,
    const float* __restrict__ gamma, const float* __restrict__ beta,
    const float* __restrict__ rmean, const float* __restrict__ rvar,
    unsigned short* __restrict__ t)
{
    __shared__ float Wst[64 * 68];    // Wst[c*68 + o] = W[o][c]
    __shared__ float feats[64 * 64];  // feats[c*64 + nl]
    const int tid = threadIdx.x;
    const int blk = blockIdx.x;       // 1024 blocks: b * 512 + ntile
    const int b   = blk >> 9;
    const int n0  = (blk & 511) << 6;

    {
        const int lo = tid & 63;
        const int hi = tid >> 6;
        #pragma unroll
        for (int i = 0; i < 16; ++i) {
            const int o = hi + i * 4;
            Wst[lo * 68 + o] = W[o * 64 + lo];
        }
        const float* fp = feature + (size_t)b * Cc * Nn + n0 + lo;
        #pragma unroll
        for (int i = 0; i < 16; ++i) {
            const int c = hi + i * 4;
            feats[c * 64 + lo] = fp[(size_t)c * Nn];
        }
    }
    __syncthreads();

    const int tx = tid & 15;
    const int ty = tid >> 4;
    const int o0  = tx * 4;
    const int nl0 = ty * 4;

    float acc[4][4];
    #pragma unroll
    for (int j = 0; j < 4; ++j)
        #pragma unroll
        for (int i = 0; i < 4; ++i) acc[j][i] = 0.0f;

    #pragma unroll
    for (int c = 0; c < 64; ++c) {
        const float4 a4 = *(const float4*)&Wst[c * 68 + o0];
        const float4 b4 = *(const float4*)&feats[c * 64 + nl0];
        const float av[4] = {a4.x, a4.y, a4.z, a4.w};
        const float bv[4] = {b4.x, b4.y, b4.z, b4.w};
        #pragma unroll
        for (int j = 0; j < 4; ++j)
            #pragma unroll
            for (int i = 0; i < 4; ++i)
                acc[j][i] = fmaf(av[i], bv[j], acc[j][i]);
    }

    const float4 g4 = *(const float4*)&gamma[o0];
    const float4 be4 = *(const float4*)&beta[o0];
    const float4 m4 = *(const float4*)&rmean[o0];
    const float4 v4 = *(const float4*)&rvar[o0];
    float inv[4], bias[4];
    inv[0] = g4.x / sqrtf(v4.x + BN_EPS);
    inv[1] = g4.y / sqrtf(v4.y + BN_EPS);
    inv[2] = g4.z / sqrtf(v4.z + BN_EPS);
    inv[3] = g4.w / sqrtf(v4.w + BN_EPS);
    bias[0] = be4.x - m4.x * inv[0];
    bias[1] = be4.y - m4.y * inv[1];
    bias[2] = be4.z - m4.z * inv[2];
    bias[3] = be4.w - m4.w * inv[3];

    unsigned short* tp = t + ((size_t)b * Nn + n0 + nl0) * 64 + o0;
    #pragma unroll
    for (int j = 0; j < 4; ++j) {
        ushort4 ov;
        ov.x = f2bf(fmaxf(fmaf(inv[0], acc[j][0], bias[0]), 0.0f));
        ov.y = f2bf(fmaxf(fmaf(inv[1], acc[j][1], bias[1]), 0.0f));
        ov.z = f2bf(fmaxf(fmaf(inv[2], acc[j][2], bias[2]), 0.0f));
        ov.w = f2bf(fmaxf(fmaf(inv[3], acc[j][3], bias[3]), 0.0f));
        *(ushort4*)&tp[j * 64] = ov;   // 8B/lane
    }
}

// Kernel 2: out[b][o][n] = t[b][n][o] + sum_j t[b][idx[b][n][j]][o]
// 16 waves/block, wave owns 4 points: lane=(p,q), p=point, q=o-quad.
// 17 independent 8B bf16 gathers per lane stay in flight; fp32 accumulate.
__global__ __launch_bounds__(1024) void spe_gather_sum(
    const unsigned short* __restrict__ t, const int* __restrict__ idx,
    float* __restrict__ out)
{
    __shared__ float s[64 * 65];      // s[nl*65 + o]; stride 65 -> conflict-free transpose
    const int tid  = threadIdx.x;
    const int wv   = tid >> 6;        // wave 0..15
    const int lane = tid & 63;
    const int p    = lane >> 4;       // 0..3 point within group
    const int q    = lane & 15;       // o-quad (o = q*4..q*4+3)
    const int blk  = blockIdx.x;
    const int b    = blk >> 9;
    const int n0   = (blk & 511) << 6;
    const int ng   = n0 + wv * 4;     // this wave's 4-point group base

    const unsigned short* tb = t + (size_t)b * Nn * 64;

    // 4 points x 16 neighbors = 64 ints, one fully-coalesced 256B load
    const int myidx = idx[((size_t)b * Nn + ng) * Kk + lane];

    const int n = ng + p;
    const ushort4 c4 = *(const ushort4*)&tb[(size_t)n * 64 + q * 4];   // center tap
    float ax = bf2f(c4.x), ay = bf2f(c4.y), az = bf2f(c4.z), aw = bf2f(c4.w);
    #pragma unroll
    for (int j = 0; j < 16; ++j) {
        const int nj = __shfl(myidx, p * 16 + j);
        const ushort4 v = *(const ushort4*)&tb[(size_t)nj * 64 + q * 4];
        ax += bf2f(v.x); ay += bf2f(v.y); az += bf2f(v.z); aw += bf2f(v.w);
    }

    const int nl = wv * 4 + p;
    float* sp = &s[nl * 65 + q * 4];
    sp[0] = ax; sp[1] = ay; sp[2] = az; sp[3] = aw;
    __syncthreads();

    // transpose write-out: lanes over n => coalesced 256B stores
    const int nl2 = tid & 63;
    const int ob  = tid >> 6;          // 0..15
    float* op = out + (size_t)b * Oo * Nn + n0 + nl2;
    #pragma unroll
    for (int i = 0; i < 4; ++i) {
        const int o = ob * 4 + i;
        op[(size_t)o * Nn] = s[nl2 * 65 + o];
    }
}

extern "C" void kernel_launch(void* const* d_in, const int* in_sizes, int n_in,
                              void* d_out, int out_size, void* d_ws, size_t ws_size,
                              hipStream_t stream) {
    const float* feature = (const float*)d_in[0];
    const int*   nidx    = (const int*)d_in[1];
    const float* W       = (const float*)d_in[2];
    const float* gamma   = (const float*)d_in[3];
    const float* beta    = (const float*)d_in[4];
    const float* rmean   = (const float*)d_in[5];
    const float* rvar    = (const float*)d_in[6];
    float* out = (float*)d_out;
    unsigned short* t = (unsigned short*)d_ws;   // B*N*O*2 = 8 MiB bf16

    const int nblocks = Bb * (Nn / 64);  // 1024
    spe_gemm_bn_relu<<<nblocks, 256, 0, stream>>>(feature, W, gamma, beta, rmean, rvar, t);
    spe_gather_sum<<<nblocks, 1024, 0, stream>>>(t, nidx, out);
}

// Round 4
// 95.527 us; speedup vs baseline: 1.8145x; 1.0395x over previous
//
#include <hip/hip_runtime.h>

#define BN_EPS 1e-5f

constexpr int Bb = 2;
constexpr int Cc = 64;
constexpr int Nn = 32768;
constexpr int Kk = 16;
constexpr int Oo = 64;

typedef __attribute__((ext_vector_type(8))) short v8s;   // 8 x bf16
typedef __attribute__((ext_vector_type(4))) float v4f;   // MFMA C/D

__device__ __forceinline__ unsigned short f2bf(float f) {
    unsigned u = __float_as_uint(f);
    return (unsigned short)((u + 0x7FFFu + ((u >> 16) & 1u)) >> 16);  // RNE
}
__device__ __forceinline__ float bf2f(unsigned short h) {
    return __uint_as_float(((unsigned)h) << 16);
}

// Kernel 1: per block, one 64x64x64 matmul via mfma_f32_16x16x32_bf16.
// t[b][n][o] = bf16(relu(inv[o]*(W[o,:].f[:,n]) + bias[o])), o-contiguous rows.
// b = blk&1: with round-robin blk->XCD, each XCD serves one batch (L2 locality,
// pre-warms the L2 slice the gather will hit).
__global__ __launch_bounds__(256) void spe_gemm_mfma(
    const float* __restrict__ feature, const float* __restrict__ W,
    const float* __restrict__ gamma, const float* __restrict__ beta,
    const float* __restrict__ rmean, const float* __restrict__ rvar,
    unsigned short* __restrict__ t)
{
    __shared__ unsigned short fA[64][68];   // fA[n][c] bf16, +4 pad: frag reads <=4-way, rare
    __shared__ unsigned short fB[64][68];   // fB[o][c] bf16 (= B[k=c][j=o] operand)
    const int tid = threadIdx.x;
    const int blk = blockIdx.x;             // 1024 = 2 batches x 512 tiles
    const int b   = blk & 1;
    const int n0  = (blk >> 1) << 6;

    // ---- stage: coalesced f32 global reads, bf16 LDS writes ----
    {
        const int nl = tid & 63;            // lane-contiguous over n
        const int h  = tid >> 6;            // wave id 0..3
        const float* fp = feature + (size_t)b * Cc * Nn + n0 + nl;
        #pragma unroll
        for (int i = 0; i < 16; ++i) {
            const int c = h * 16 + i;
            fA[nl][c] = f2bf(fp[(size_t)c * Nn]);     // transpose [c][n]->[n][c]
        }
        const int c2 = tid & 63;            // lane-contiguous over c (W rows are c-contig)
        #pragma unroll
        for (int i = 0; i < 16; ++i) {
            const int o = h + i * 4;
            fB[o][c2] = f2bf(W[o * 64 + c2]);
        }
    }
    __syncthreads();

    // ---- MFMA: wave wv owns n-rows [wv*16, wv*16+16), all 64 o in 4 tiles ----
    const int wv   = tid >> 6;
    const int lane = tid & 63;
    const int q    = lane >> 4;     // quad
    const int r16  = lane & 15;

    union U8 { ushort4 u4[2]; v8s v; };
    const int am = wv * 16 + r16;   // A row m = point row
    U8 a0, a1;
    a0.u4[0] = *(const ushort4*)&fA[am][q * 8];
    a0.u4[1] = *(const ushort4*)&fA[am][q * 8 + 4];
    a1.u4[0] = *(const ushort4*)&fA[am][32 + q * 8];
    a1.u4[1] = *(const ushort4*)&fA[am][32 + q * 8 + 4];

    v4f acc[4];
    #pragma unroll
    for (int ot = 0; ot < 4; ++ot) {
        const int bo = ot * 16 + r16;   // B col j = o
        U8 b0, b1;
        b0.u4[0] = *(const ushort4*)&fB[bo][q * 8];
        b0.u4[1] = *(const ushort4*)&fB[bo][q * 8 + 4];
        b1.u4[0] = *(const ushort4*)&fB[bo][32 + q * 8];
        b1.u4[1] = *(const ushort4*)&fB[bo][32 + q * 8 + 4];
        v4f c = {0.f, 0.f, 0.f, 0.f};
        c = __builtin_amdgcn_mfma_f32_16x16x32_bf16(a0.v, b0.v, c, 0, 0, 0);
        c = __builtin_amdgcn_mfma_f32_16x16x32_bf16(a1.v, b1.v, c, 0, 0, 0);
        acc[ot] = c;
    }

    // ---- BN + ReLU epilogue; C/D layout: col=lane&15, row=quad*4+reg ----
    #pragma unroll
    for (int ot = 0; ot < 4; ++ot) {
        const int o = ot * 16 + r16;
        const float inv  = gamma[o] / sqrtf(rvar[o] + BN_EPS);
        const float bias = beta[o] - rmean[o] * inv;
        unsigned short* tp = t + ((size_t)b * Nn + n0 + wv * 16 + q * 4) * 64 + o;
        #pragma unroll
        for (int r = 0; r < 4; ++r)
            tp[(size_t)r * 64] = f2bf(fmaxf(fmaf(inv, acc[ot][r], bias), 0.0f));
    }
}

// Kernel 2: out[b][o][n] = t[b][n][o] + sum_j t[b][idx[b][n][j]][o]
// 16 waves/block, wave owns 4 points: lane=(p,q), p=point, q=o-quad.
// 17 independent 8B bf16 gathers in flight; fp32 accumulate.
// b = blk&1: per-XCD gather working set = one batch's 4 MB t = one L2.
__global__ __launch_bounds__(1024) void spe_gather_sum(
    const unsigned short* __restrict__ t, const int* __restrict__ idx,
    float* __restrict__ out)
{
    __shared__ float s[64 * 65];      // stride 65 -> conflict-free transpose
    const int tid  = threadIdx.x;
    const int wv   = tid >> 6;        // 0..15
    const int lane = tid & 63;
    const int p    = lane >> 4;
    const int q    = lane & 15;
    const int blk  = blockIdx.x;
    const int b    = blk & 1;
    const int n0   = ((blk >> 1) & 511) << 6;
    const int ng   = n0 + wv * 4;

    const unsigned short* tb = t + (size_t)b * Nn * 64;

    const int myidx = idx[((size_t)b * Nn + ng) * Kk + lane];  // 64 ints, 256B coalesced

    const int n = ng + p;
    const ushort4 c4 = *(const ushort4*)&tb[(size_t)n * 64 + q * 4];
    float ax = bf2f(c4.x), ay = bf2f(c4.y), az = bf2f(c4.z), aw = bf2f(c4.w);
    #pragma unroll
    for (int j = 0; j < 16; ++j) {
        const int nj = __shfl(myidx, p * 16 + j);
        const ushort4 v = *(const ushort4*)&tb[(size_t)nj * 64 + q * 4];
        ax += bf2f(v.x); ay += bf2f(v.y); az += bf2f(v.z); aw += bf2f(v.w);
    }

    const int nl = wv * 4 + p;
    float* sp = &s[nl * 65 + q * 4];
    sp[0] = ax; sp[1] = ay; sp[2] = az; sp[3] = aw;
    __syncthreads();

    const int nl2 = tid & 63;
    const int ob  = tid >> 6;
    float* op = out + (size_t)b * Oo * Nn + n0 + nl2;
    #pragma unroll
    for (int i = 0; i < 4; ++i) {
        const int o = ob * 4 + i;
        op[(size_t)o * Nn] = s[nl2 * 65 + o];   // coalesced 256B stores
    }
}

extern "C" void kernel_launch(void* const* d_in, const int* in_sizes, int n_in,
                              void* d_out, int out_size, void* d_ws, size_t ws_size,
                              hipStream_t stream) {
    const float* feature = (const float*)d_in[0];
    const int*   nidx    = (const int*)d_in[1];
    const float* W       = (const float*)d_in[2];
    const float* gamma   = (const float*)d_in[3];
    const float* beta    = (const float*)d_in[4];
    const float* rmean   = (const float*)d_in[5];
    const float* rvar    = (const float*)d_in[6];
    float* out = (float*)d_out;
    unsigned short* t = (unsigned short*)d_ws;   // B*N*O*2 = 8 MiB bf16

    const int nblocks = Bb * (Nn / 64);  // 1024
    spe_gemm_mfma<<<nblocks, 256, 0, stream>>>(feature, W, gamma, beta, rmean, rvar, t);
    spe_gather_sum<<<nblocks, 1024, 0, stream>>>(t, nidx, out);
}